// Round 3
// baseline (186.451 us; speedup 1.0000x reference)
//
#include <hip/hip_runtime.h>

// CompGraphConv round 12: fuse GEMM into sort_gather (4 -> 3 dispatches).
//
// Round 11 (186 us): sort_gather 42.8 us (VALU 45%, HBM 27%, occ 36%) is
// near its structural cost; the next waste is the A round-trip: sort_gather
// writes A's window block (25.6 MB), gemv_mfma re-reads all of A (38.4 MB)
// in a separate dispatch. But each sort_gather wave owns 8 pairs = 16 nodes
// = exactly one MFMA tile, and the per-key degrees live in LDS cnt[].
// Fusion: wave-private LDS tile [16][136] receives the window sums; the
// same wave then loads A-frags (y from ytab, windows from LDS), runs the
// 4x6 mfma_f32_16x16x32_f16 chain vs Wf, biases from cnt, writes out.
// gemv_mfma deleted; prep writes only ytab; r_transform in last prep block.

#define DF 64
#define BCAP 2560           // entries per bucket: mean 1534, +26 sigma
#define CPAD 16             // ints per cursor (one 64B line each)
#define NBMAX 1024          // max coarse buckets (NB = ceil(2N/256) = 782)
#define SCHUNK 4096         // edges per scatter block
typedef _Float16 f16;
typedef f16 f16x8 __attribute__((ext_vector_type(8)));
typedef f16 f16x4 __attribute__((ext_vector_type(4)));
typedef f16 f16x2 __attribute__((ext_vector_type(2)));
typedef float f32x4 __attribute__((ext_vector_type(4)));

// K1: blocks [0,SB) = block-local LDS edge binning; blocks [SB,SB+PB) =
// y = x - r into compact ytab + W -> f16 Wf; last block also r_transform.
__global__ __launch_bounds__(512) void scatter_prep(
    const int* __restrict__ src, const int* __restrict__ dst,
    int* __restrict__ cur, unsigned int* __restrict__ pairBuf,
    int E, int half, int NB, int SB, int PB,
    const float* __restrict__ x, const float* __restrict__ r,
    f16* __restrict__ ytab,
    const float* __restrict__ W_S, const float* __restrict__ W_O,
    const float* __restrict__ W_I, f16* __restrict__ Wf,
    const float* __restrict__ W_R, const float* __restrict__ b_R,
    float* __restrict__ out, int N) {
    int t = threadIdx.x;
    if ((int)blockIdx.x < SB) {
        __shared__ int cnt[NBMAX];        // histogram, then reused as cursor
        int e0 = blockIdx.x * SCHUNK;
        int n = E - e0; if (n > SCHUNK) n = SCHUNK;
        for (int k = t; k < NBMAX; k += 512) cnt[k] = 0;
        __syncthreads();

        unsigned int ent[SCHUNK / 512];
        int bk[SCHUNK / 512];
        #pragma unroll
        for (int i = 0; i < SCHUNK / 512; i++) {
            int idx = t + i * 512;
            bk[i] = -1;
            if (idx < n) {
                int e = e0 + idx;
                int s = __builtin_nontemporal_load(src + e);
                int d = __builtin_nontemporal_load(dst + e);
                int key = (d << 1) | (e >= half ? 1 : 0);
                int b = key >> 8;         // b < NB <= NBMAX
                ent[i] = (unsigned int)s | ((unsigned int)(key & 255) << 24);
                bk[i] = b;
                atomicAdd(&cnt[b], 1);
            }
        }
        __syncthreads();
        // reserve per-bucket runs: ONE global atomic per (block,bucket)
        for (int k = t; k < NB; k += 512) {
            int c = cnt[k];
            cnt[k] = (c > 0) ? atomicAdd(&cur[k * CPAD], c) : 0;
        }
        __syncthreads();
        #pragma unroll
        for (int i = 0; i < SCHUNK / 512; i++) {
            if (bk[i] >= 0) {
                int pos = atomicAdd(&cnt[bk[i]], 1);
                if (pos < BCAP)
                    pairBuf[(size_t)bk[i] * BCAP + pos] = ent[i];
            }
        }
    } else {
        int tt = ((int)blockIdx.x - SB) * 512 + t;
        int ny = N * 32;                  // f16x2 pairs of y
        if (tt < ny) {
            int v = tt >> 5, k = (tt & 31) * 2;
            float y0 = x[(size_t)v * DF + k]     - r[k];
            float y1 = x[(size_t)v * DF + k + 1] - r[k + 1];
            f16x2 p = {(f16)y0, (f16)y1};
            *(f16x2*)(ytab + (size_t)v * 64 + k) = p;
        }
        if (tt < 6144) {                  // 3*4096 weight elems as pairs
            int w = tt / 2048;
            int i = (tt % 2048) * 2;
            const float* W = (w == 0) ? W_S : (w == 1) ? W_O : W_I;
            f16x2 p = {(f16)W[i], (f16)W[i + 1]};
            *(f16x2*)(Wf + w * 4096 + i) = p;
        }
        if ((int)blockIdx.x == SB + PB - 1 && t < 64) {
            float s = b_R[t];
            #pragma unroll 16
            for (int k = 0; k < 64; k++) s += r[k] * W_R[t * 64 + k];
            out[(size_t)N * DF + t] = s;
        }
    }
}

// K2: per-bucket counting sort (sorted list in LDS) + gather + fused MFMA
// epilogue. 512 thr = 8 waves; wave wid owns pairs wid*8..wid*8+7 = its own
// 16-node MFMA tile. Window sums go to a wave-private LDS tile [16][136]
// (stride 272B = 68 dwords == 4 mod 32 -> <=2-way conflicts on b64 stores,
// 8-way only on the 4 per-tile ds_read_b128, negligible). Then 4x6
// mfma_f32_16x16x32_f16 vs Wf, bias from LDS cnt, store out. No gemv pass.
__global__ __launch_bounds__(512) void sort_gather_gemv(
    unsigned int* __restrict__ pairBuf, const int* __restrict__ cur,
    const f16* __restrict__ Y, const f16* __restrict__ Wf,
    const float* __restrict__ b_O, const float* __restrict__ b_I,
    const float* __restrict__ b_S, float* __restrict__ out,
    int N, int M) {
    __shared__ unsigned int S[2048 + 8];  // sorted src, +8 zero pad for tail
    __shared__ int cnt[256];
    __shared__ int pos[256];
    __shared__ f16 T[8][16][136];         // wave-private window tiles
    int b = blockIdx.x, t = threadIdx.x;
    if (t < 256) cnt[t] = 0;
    __syncthreads();
    int n = cur[b * CPAD];
    if (n > 2048) n = 2048;               // +13 sigma cap, statistically never
    const unsigned int* seg = pairBuf + (size_t)b * BCAP;
    unsigned int ent[4];                  // n<=2048, 512 thr -> <=4 each
    int ne = 0;
    for (int idx = t; idx < n; idx += 512) {
        unsigned int p = seg[idx];
        ent[ne++] = p;
        atomicAdd(&cnt[p >> 24], 1);
    }
    __syncthreads();
    int v = 0, incl = 0;
    if (t < 256) { v = cnt[t]; pos[t] = v; }
    __syncthreads();
    #pragma unroll
    for (int s = 1; s < 256; s <<= 1) {
        int u = 0;
        if (t < 256 && t >= s) u = pos[t - s];
        __syncthreads();
        if (t < 256) pos[t] += u;
        __syncthreads();
    }
    if (t < 256) incl = pos[t];
    __syncthreads();
    if (t < 256) pos[t] = incl - v;       // exclusive cursor for the scatter
    __syncthreads();
    for (int j = 0; j < ne; j++) {
        unsigned int p = ent[j];
        int loc = atomicAdd(&pos[p >> 24], 1);
        S[loc] = p & 0xFFFFFFu;           // dense sorted src, in LDS
    }
    __syncthreads();
    if (t < 8) S[n + t] = 0;              // zero tail pad (n+7 < 2056)
    __syncthreads();
    // post-scatter: pos[l] == inclusive end of run l; cnt[l] == its length

    const int wid = t >> 6, lane = t & 63;
    const int g = lane >> 4, q = lane & 15;
    const int vbase = b * 128;
    const f16x2 zz = {(f16)0.f, (f16)0.f};

    for (int i = 0; i < 8; i++) {
        int pp = wid * 8 + i;             // pair index within bucket
        int v0 = vbase + 2 * pp, v1 = v0 + 1;
        if (v0 >= N) break;
        bool hasV1 = (v1 < N);
        int l0 = 4 * pp;
        int dO0 = cnt[l0], dI0 = cnt[l0 + 1];
        int dO1 = hasV1 ? cnt[l0 + 2] : 0;
        int dI1 = hasV1 ? cnt[l0 + 3] : 0;
        int s0 = pos[l0] - dO0;           // base of run l0 (runs contiguous)
        int t1 = s0 + dO0, t2 = t1 + dI0, t3 = t2 + dO1;
        int end = t3 + dI1;

        f16x2 aA0 = zz, aA1 = zz, a10 = zz, a11 = zz,
              a20 = zz, a21 = zz, a30 = zz, a31 = zz;

        int e = s0;
        for (; e + 8 <= end; e += 8) {
            int eA = e + g, eB = e + g + 4;
            int iA = (int)S[eA];
            int iB = (int)S[eB];
            const f16x2* pa = (const f16x2*)(Y + ((size_t)iA << 6) + 4 * q);
            const f16x2* pb = (const f16x2*)(Y + ((size_t)iB << 6) + 4 * q);
            f16x2 va0 = pa[0], va1 = pa[1];
            f16x2 vb0 = pb[0], vb1 = pb[1];
            aA0 += va0; aA1 += va1;
            a10 += (eA >= t1) ? va0 : zz;  a11 += (eA >= t1) ? va1 : zz;
            a20 += (eA >= t2) ? va0 : zz;  a21 += (eA >= t2) ? va1 : zz;
            a30 += (eA >= t3) ? va0 : zz;  a31 += (eA >= t3) ? va1 : zz;
            aA0 += vb0; aA1 += vb1;
            a10 += (eB >= t1) ? vb0 : zz;  a11 += (eB >= t1) ? vb1 : zz;
            a20 += (eB >= t2) ? vb0 : zz;  a21 += (eB >= t2) ? vb1 : zz;
            a30 += (eB >= t3) ? vb0 : zz;  a31 += (eB >= t3) ? vb1 : zz;
        }
        if (e < end) {                    // masked tail (wave-uniform branch)
            int eA = e + g, eB = e + g + 4;
            bool inA = (eA < end), inB = (eB < end);
            // OOB lanes read the zero pad (eB <= end+6 <= n+6 < 2056)
            int iA = (int)S[eA];
            int iB = (int)S[eB];
            const f16x2* pa = (const f16x2*)(Y + ((size_t)iA << 6) + 4 * q);
            const f16x2* pb = (const f16x2*)(Y + ((size_t)iB << 6) + 4 * q);
            f16x2 va0 = pa[0], va1 = pa[1];
            f16x2 vb0 = pb[0], vb1 = pb[1];
            aA0 += inA ? va0 : zz; aA1 += inA ? va1 : zz;
            a10 += (inA && eA >= t1) ? va0 : zz;  a11 += (inA && eA >= t1) ? va1 : zz;
            a20 += (inA && eA >= t2) ? va0 : zz;  a21 += (inA && eA >= t2) ? va1 : zz;
            a30 += (inA && eA >= t3) ? va0 : zz;  a31 += (inA && eA >= t3) ? va1 : zz;
            aA0 += inB ? vb0 : zz; aA1 += inB ? vb1 : zz;
            a10 += (inB && eB >= t1) ? vb0 : zz;  a11 += (inB && eB >= t1) ? vb1 : zz;
            a20 += (inB && eB >= t2) ? vb0 : zz;  a21 += (inB && eB >= t2) ? vb1 : zz;
            a30 += (inB && eB >= t3) ? vb0 : zz;  a31 += (inB && eB >= t3) ? vb1 : zz;
        }

        // butterfly over the 4 groups, on packed dwords (bit-exact shuffles)
        f16x2 acc[8] = {aA0, aA1, a10, a11, a20, a21, a30, a31};
        #pragma unroll
        for (int k = 0; k < 8; k++) {
            int w = __builtin_bit_cast(int, acc[k]);
            f16x2 u16 = __builtin_bit_cast(f16x2, __shfl_xor(w, 16, 64));
            acc[k] += u16;
            w = __builtin_bit_cast(int, acc[k]);
            f16x2 u32 = __builtin_bit_cast(f16x2, __shfl_xor(w, 32, 64));
            acc[k] += u32;
        }
        // window sums (packed): d0=All-G1, d1=G1-G2, d2=G2-G3, d3=G3
        f16x2 d0l = acc[0] - acc[2], d0h = acc[1] - acc[3];
        f16x2 d1l = acc[2] - acc[4], d1h = acc[3] - acc[5];
        f16x2 d2l = acc[4] - acc[6], d2h = acc[5] - acc[7];
        f16x2 d3l = acc[6],          d3h = acc[7];
        f16x2 wl01 = (g == 0) ? d0l : d1l, wh01 = (g == 0) ? d0h : d1h;
        f16x2 wl23 = (g == 2) ? d2l : d3l, wh23 = (g == 2) ? d2h : d3h;
        f16x2 wl = (g < 2) ? wl01 : wl23,  wh = (g < 2) ? wh01 : wh23;

        int vtgt = (g < 2) ? v0 : v1;
        float d01 = (g == 0) ? (float)dO0 : (float)dI0;
        float d23 = (g == 2) ? (float)dO1 : (float)dI1;
        float dd = (g < 2) ? d01 : d23;
        if (vtgt < N) {
            const f16x2* yp = (const f16x2*)(Y + ((size_t)vtgt << 6) + 4 * q);
            f16x2 y0 = yp[0], y1 = yp[1];
            f16x4 res;
            res[0] = (f16)((float)wl[0] - dd * (float)y0[0]);
            res[1] = (f16)((float)wl[1] - dd * (float)y0[1]);
            res[2] = (f16)((float)wh[0] - dd * (float)y1[0]);
            res[3] = (f16)((float)wh[1] - dd * (float)y1[1]);
            int row = 2 * i + (g >> 1);
            int col = (g & 1) * 64 + 4 * q;
            *(f16x4*)&T[wid][row][col] = res;    // wave-private, no barrier
        }
    }

    // ---- fused MFMA epilogue: wave wid's 16-node tile ----
    const int mlane = lane & 15;
    const int koff = (lane >> 4) * 8;
    const int vtile = vbase + wid * 16;
    if (vtile < N) {
        int va = vtile + mlane; if (va >= N) va = N - 1;
        f16x8 af[6];
        af[0] = *(const f16x8*)(Y + ((size_t)va << 6) + koff);
        af[1] = *(const f16x8*)(Y + ((size_t)va << 6) + 32 + koff);
        #pragma unroll
        for (int s = 2; s < 6; s++)
            af[s] = *(const f16x8*)&T[wid][mlane][(s - 2) * 32 + koff];

        f32x4 accs[4];
        #pragma unroll
        for (int c = 0; c < 4; c++) {
            f32x4 acc = {0.f, 0.f, 0.f, 0.f};
            #pragma unroll
            for (int s = 0; s < 6; s++) {
                int k = s * 32 + koff;
                const f16* bp = Wf + (k >> 6) * 4096 + (c * 16 + mlane) * 64 + (k & 63);
                f16x8 bf = *(const f16x8*)bp;
                acc = __builtin_amdgcn_mfma_f32_16x16x32_f16(af[s], bf, acc, 0, 0, 0);
            }
            accs[c] = acc;
        }

        // C/D layout: col = lane&15, row = (lane>>4)*4 + reg
        const int mrow0 = (lane >> 4) * 4;
        #pragma unroll
        for (int reg = 0; reg < 4; reg++) {
            int vl = wid * 16 + mrow0 + reg;
            int vv = vbase + vl;
            if (vv >= N) continue;
            int lk = 4 * (vl >> 1) + 2 * (vl & 1);
            float cO = (float)cnt[lk], cI = (float)cnt[lk + 1];
            #pragma unroll
            for (int c = 0; c < 4; c++) {
                int j = c * 16 + mlane;
                out[(size_t)vv * DF + j] = accs[c][reg] + b_S[j] + cO * b_O[j] + cI * b_I[j];
            }
        }
    }
}

extern "C" void kernel_launch(void* const* d_in, const int* in_sizes, int n_in,
                              void* d_out, int out_size, void* d_ws, size_t ws_size,
                              hipStream_t stream) {
    const float* x   = (const float*)d_in[0];
    const float* r   = (const float*)d_in[1];
    const int*   src = (const int*)d_in[2];
    const int*   dst = (const int*)d_in[3];
    const float* W_O = (const float*)d_in[4];
    const float* b_O = (const float*)d_in[5];
    const float* W_I = (const float*)d_in[6];
    const float* b_I = (const float*)d_in[7];
    const float* W_S = (const float*)d_in[8];
    const float* b_S = (const float*)d_in[9];
    const float* W_R = (const float*)d_in[10];
    const float* b_R = (const float*)d_in[11];
    float* out = (float*)d_out;

    const int N = in_sizes[0] / DF;
    const int E = in_sizes[2];
    const int half = E / 2;
    const int M = 2 * N;                 // keys: (dst<<1)|isI
    const int NB = (M + 255) >> 8;       // 256 keys per bucket (NB <= NBMAX)

    // ws: Wf[3*4096] f16 | ytab[N*64] f16 | cur[NB*CPAD] | pairBuf[NB*BCAP]
    f16* Wf = (f16*)d_ws;
    f16* ytab = Wf + 3 * 4096;
    int* cur = (int*)(ytab + (size_t)N * 64);
    unsigned int* pairBuf = (unsigned int*)(cur + (size_t)NB * CPAD);

    hipMemsetAsync(cur, 0, (size_t)NB * CPAD * sizeof(int), stream);

    const int SB = (E + SCHUNK - 1) / SCHUNK;          // scatter blocks
    const int PB = (N * 32 + 511) / 512;               // prep blocks
    scatter_prep<<<SB + PB, 512, 0, stream>>>(src, dst, cur, pairBuf,
                                              E, half, NB, SB, PB,
                                              x, r, ytab,
                                              W_S, W_O, W_I, Wf,
                                              W_R, b_R, out, N);

    sort_gather_gemv<<<NB, 512, 0, stream>>>(pairBuf, cur, ytab, Wf,
                                             b_O, b_I, b_S, out, N, M);
}

// Round 4
// 186.217 us; speedup vs baseline: 1.0013x; 1.0013x over previous
//
#include <hip/hip_runtime.h>

// CompGraphConv round 13: fused kernel at 16 waves/block for wave residency.
//
// Round 12 (186 us, neutral): fusing gemv into sort_gather killed 38 MB of
// A-refetch but the fused kernel ran at 1.34 TB/s effective (dur ==
// traffic/BW), down from 2.15, at the same 36% occupancy (~12 waves/CU:
// 8-wave blocks, grid-limited ~3 blocks/CU). The random 128B ytab gathers
// are latency-bound -> effective BW scales with resident waves.
// Fix: 1024-thread blocks (16 waves x 4 pairs). 2 blocks/CU x 16 waves =
// 32 waves/CU (wave-slot max). A 16-node MFMA tile is now produced by a
// wave PAIR: one __syncthreads() between gather and epilogue; each wave of
// the pair computes 2 of the tile's 4 column-blocks.

#define DF 64
#define BCAP 2560           // entries per bucket: mean 1534, +26 sigma
#define CPAD 16             // ints per cursor (one 64B line each)
#define NBMAX 1024          // max coarse buckets (NB = ceil(2N/256) = 782)
#define SCHUNK 4096         // edges per scatter block
typedef _Float16 f16;
typedef f16 f16x8 __attribute__((ext_vector_type(8)));
typedef f16 f16x4 __attribute__((ext_vector_type(4)));
typedef f16 f16x2 __attribute__((ext_vector_type(2)));
typedef float f32x4 __attribute__((ext_vector_type(4)));

// K1: blocks [0,SB) = block-local LDS edge binning; blocks [SB,SB+PB) =
// y = x - r into compact ytab + W -> f16 Wf; last block also r_transform.
__global__ __launch_bounds__(512) void scatter_prep(
    const int* __restrict__ src, const int* __restrict__ dst,
    int* __restrict__ cur, unsigned int* __restrict__ pairBuf,
    int E, int half, int NB, int SB, int PB,
    const float* __restrict__ x, const float* __restrict__ r,
    f16* __restrict__ ytab,
    const float* __restrict__ W_S, const float* __restrict__ W_O,
    const float* __restrict__ W_I, f16* __restrict__ Wf,
    const float* __restrict__ W_R, const float* __restrict__ b_R,
    float* __restrict__ out, int N) {
    int t = threadIdx.x;
    if ((int)blockIdx.x < SB) {
        __shared__ int cnt[NBMAX];        // histogram, then reused as cursor
        int e0 = blockIdx.x * SCHUNK;
        int n = E - e0; if (n > SCHUNK) n = SCHUNK;
        for (int k = t; k < NBMAX; k += 512) cnt[k] = 0;
        __syncthreads();

        unsigned int ent[SCHUNK / 512];
        int bk[SCHUNK / 512];
        #pragma unroll
        for (int i = 0; i < SCHUNK / 512; i++) {
            int idx = t + i * 512;
            bk[i] = -1;
            if (idx < n) {
                int e = e0 + idx;
                int s = __builtin_nontemporal_load(src + e);
                int d = __builtin_nontemporal_load(dst + e);
                int key = (d << 1) | (e >= half ? 1 : 0);
                int b = key >> 8;         // b < NB <= NBMAX
                ent[i] = (unsigned int)s | ((unsigned int)(key & 255) << 24);
                bk[i] = b;
                atomicAdd(&cnt[b], 1);
            }
        }
        __syncthreads();
        // reserve per-bucket runs: ONE global atomic per (block,bucket)
        for (int k = t; k < NB; k += 512) {
            int c = cnt[k];
            cnt[k] = (c > 0) ? atomicAdd(&cur[k * CPAD], c) : 0;
        }
        __syncthreads();
        #pragma unroll
        for (int i = 0; i < SCHUNK / 512; i++) {
            if (bk[i] >= 0) {
                int pos = atomicAdd(&cnt[bk[i]], 1);
                if (pos < BCAP)
                    pairBuf[(size_t)bk[i] * BCAP + pos] = ent[i];
            }
        }
    } else {
        int tt = ((int)blockIdx.x - SB) * 512 + t;
        int ny = N * 32;                  // f16x2 pairs of y
        if (tt < ny) {
            int v = tt >> 5, k = (tt & 31) * 2;
            float y0 = x[(size_t)v * DF + k]     - r[k];
            float y1 = x[(size_t)v * DF + k + 1] - r[k + 1];
            f16x2 p = {(f16)y0, (f16)y1};
            *(f16x2*)(ytab + (size_t)v * 64 + k) = p;
        }
        if (tt < 6144) {                  // 3*4096 weight elems as pairs
            int w = tt / 2048;
            int i = (tt % 2048) * 2;
            const float* W = (w == 0) ? W_S : (w == 1) ? W_O : W_I;
            f16x2 p = {(f16)W[i], (f16)W[i + 1]};
            *(f16x2*)(Wf + w * 4096 + i) = p;
        }
        if ((int)blockIdx.x == SB + PB - 1 && t < 64) {
            float s = b_R[t];
            #pragma unroll 16
            for (int k = 0; k < 64; k++) s += r[k] * W_R[t * 64 + k];
            out[(size_t)N * DF + t] = s;
        }
    }
}

// K2: per-bucket counting sort (sorted list in LDS) + gather + fused MFMA
// epilogue. 1024 thr = 16 waves x 4 pairs; wave pair (2w,2w+1) produces
// tile w's 16 rows in T[w][16][136] (stride 272B -> <=2-way conflicts on
// the b64 stores). After one barrier, wave 2w computes col-blocks 0,1 and
// wave 2w+1 col-blocks 2,3 of tile w via mfma_f32_16x16x32_f16 vs Wf,
// bias from LDS cnt, store out. 2 blocks/CU by wave slots = 32 waves/CU.
__global__ __launch_bounds__(1024) void sort_gather_gemv(
    unsigned int* __restrict__ pairBuf, const int* __restrict__ cur,
    const f16* __restrict__ Y, const f16* __restrict__ Wf,
    const float* __restrict__ b_O, const float* __restrict__ b_I,
    const float* __restrict__ b_S, float* __restrict__ out,
    int N, int M) {
    __shared__ unsigned int S[2048 + 8];  // sorted src, +8 zero pad for tail
    __shared__ int cnt[256];
    __shared__ int pos[256];
    __shared__ f16 T[8][16][136];         // per-tile window staging
    int b = blockIdx.x, t = threadIdx.x;
    if (t < 256) cnt[t] = 0;
    __syncthreads();
    int n = cur[b * CPAD];
    if (n > 2048) n = 2048;               // +13 sigma cap, statistically never
    const unsigned int* seg = pairBuf + (size_t)b * BCAP;
    unsigned int ent[2];                  // n<=2048, 1024 thr -> <=2 each
    int ne = 0;
    for (int idx = t; idx < n; idx += 1024) {
        unsigned int p = seg[idx];
        ent[ne++] = p;
        atomicAdd(&cnt[p >> 24], 1);
    }
    __syncthreads();
    int v = 0, incl = 0;
    if (t < 256) { v = cnt[t]; pos[t] = v; }
    __syncthreads();
    #pragma unroll
    for (int s = 1; s < 256; s <<= 1) {
        int u = 0;
        if (t < 256 && t >= s) u = pos[t - s];
        __syncthreads();
        if (t < 256) pos[t] += u;
        __syncthreads();
    }
    if (t < 256) incl = pos[t];
    __syncthreads();
    if (t < 256) pos[t] = incl - v;       // exclusive cursor for the scatter
    __syncthreads();
    for (int j = 0; j < ne; j++) {
        unsigned int p = ent[j];
        int loc = atomicAdd(&pos[p >> 24], 1);
        S[loc] = p & 0xFFFFFFu;           // dense sorted src, in LDS
    }
    __syncthreads();
    if (t < 8) S[n + t] = 0;              // zero tail pad (n+7 < 2056)
    __syncthreads();
    // post-scatter: pos[l] == inclusive end of run l; cnt[l] == its length

    const int wid = t >> 6, lane = t & 63;
    const int g = lane >> 4, q = lane & 15;
    const int vbase = b * 128;
    const f16x2 zz = {(f16)0.f, (f16)0.f};

    for (int i = 0; i < 4; i++) {
        int pp = wid * 4 + i;             // pair index within bucket
        int v0 = vbase + 2 * pp, v1 = v0 + 1;
        if (v0 >= N) break;
        bool hasV1 = (v1 < N);
        int l0 = 4 * pp;
        int dO0 = cnt[l0], dI0 = cnt[l0 + 1];
        int dO1 = hasV1 ? cnt[l0 + 2] : 0;
        int dI1 = hasV1 ? cnt[l0 + 3] : 0;
        int s0 = pos[l0] - dO0;           // base of run l0 (runs contiguous)
        int t1 = s0 + dO0, t2 = t1 + dI0, t3 = t2 + dO1;
        int end = t3 + dI1;

        f16x2 aA0 = zz, aA1 = zz, a10 = zz, a11 = zz,
              a20 = zz, a21 = zz, a30 = zz, a31 = zz;

        int e = s0;
        for (; e + 8 <= end; e += 8) {
            int eA = e + g, eB = e + g + 4;
            int iA = (int)S[eA];
            int iB = (int)S[eB];
            const f16x2* pa = (const f16x2*)(Y + ((size_t)iA << 6) + 4 * q);
            const f16x2* pb = (const f16x2*)(Y + ((size_t)iB << 6) + 4 * q);
            f16x2 va0 = pa[0], va1 = pa[1];
            f16x2 vb0 = pb[0], vb1 = pb[1];
            aA0 += va0; aA1 += va1;
            a10 += (eA >= t1) ? va0 : zz;  a11 += (eA >= t1) ? va1 : zz;
            a20 += (eA >= t2) ? va0 : zz;  a21 += (eA >= t2) ? va1 : zz;
            a30 += (eA >= t3) ? va0 : zz;  a31 += (eA >= t3) ? va1 : zz;
            aA0 += vb0; aA1 += vb1;
            a10 += (eB >= t1) ? vb0 : zz;  a11 += (eB >= t1) ? vb1 : zz;
            a20 += (eB >= t2) ? vb0 : zz;  a21 += (eB >= t2) ? vb1 : zz;
            a30 += (eB >= t3) ? vb0 : zz;  a31 += (eB >= t3) ? vb1 : zz;
        }
        if (e < end) {                    // masked tail (wave-uniform branch)
            int eA = e + g, eB = e + g + 4;
            bool inA = (eA < end), inB = (eB < end);
            // OOB lanes read the zero pad (eB <= end+6 <= n+6 < 2056)
            int iA = (int)S[eA];
            int iB = (int)S[eB];
            const f16x2* pa = (const f16x2*)(Y + ((size_t)iA << 6) + 4 * q);
            const f16x2* pb = (const f16x2*)(Y + ((size_t)iB << 6) + 4 * q);
            f16x2 va0 = pa[0], va1 = pa[1];
            f16x2 vb0 = pb[0], vb1 = pb[1];
            aA0 += inA ? va0 : zz; aA1 += inA ? va1 : zz;
            a10 += (inA && eA >= t1) ? va0 : zz;  a11 += (inA && eA >= t1) ? va1 : zz;
            a20 += (inA && eA >= t2) ? va0 : zz;  a21 += (inA && eA >= t2) ? va1 : zz;
            a30 += (inA && eA >= t3) ? va0 : zz;  a31 += (inA && eA >= t3) ? va1 : zz;
            aA0 += inB ? vb0 : zz; aA1 += inB ? vb1 : zz;
            a10 += (inB && eB >= t1) ? vb0 : zz;  a11 += (inB && eB >= t1) ? vb1 : zz;
            a20 += (inB && eB >= t2) ? vb0 : zz;  a21 += (inB && eB >= t2) ? vb1 : zz;
            a30 += (inB && eB >= t3) ? vb0 : zz;  a31 += (inB && eB >= t3) ? vb1 : zz;
        }

        // butterfly over the 4 groups, on packed dwords (bit-exact shuffles)
        f16x2 acc[8] = {aA0, aA1, a10, a11, a20, a21, a30, a31};
        #pragma unroll
        for (int k = 0; k < 8; k++) {
            int w = __builtin_bit_cast(int, acc[k]);
            f16x2 u16 = __builtin_bit_cast(f16x2, __shfl_xor(w, 16, 64));
            acc[k] += u16;
            w = __builtin_bit_cast(int, acc[k]);
            f16x2 u32 = __builtin_bit_cast(f16x2, __shfl_xor(w, 32, 64));
            acc[k] += u32;
        }
        // window sums (packed): d0=All-G1, d1=G1-G2, d2=G2-G3, d3=G3
        f16x2 d0l = acc[0] - acc[2], d0h = acc[1] - acc[3];
        f16x2 d1l = acc[2] - acc[4], d1h = acc[3] - acc[5];
        f16x2 d2l = acc[4] - acc[6], d2h = acc[5] - acc[7];
        f16x2 d3l = acc[6],          d3h = acc[7];
        f16x2 wl01 = (g == 0) ? d0l : d1l, wh01 = (g == 0) ? d0h : d1h;
        f16x2 wl23 = (g == 2) ? d2l : d3l, wh23 = (g == 2) ? d2h : d3h;
        f16x2 wl = (g < 2) ? wl01 : wl23,  wh = (g < 2) ? wh01 : wh23;

        int vtgt = (g < 2) ? v0 : v1;
        float d01 = (g == 0) ? (float)dO0 : (float)dI0;
        float d23 = (g == 2) ? (float)dO1 : (float)dI1;
        float dd = (g < 2) ? d01 : d23;
        if (vtgt < N) {
            const f16x2* yp = (const f16x2*)(Y + ((size_t)vtgt << 6) + 4 * q);
            f16x2 y0 = yp[0], y1 = yp[1];
            f16x4 res;
            res[0] = (f16)((float)wl[0] - dd * (float)y0[0]);
            res[1] = (f16)((float)wl[1] - dd * (float)y0[1]);
            res[2] = (f16)((float)wh[0] - dd * (float)y1[0]);
            res[3] = (f16)((float)wh[1] - dd * (float)y1[1]);
            int row = (wid & 1) * 8 + 2 * i + (g >> 1);
            int col = (g & 1) * 64 + 4 * q;
            *(f16x4*)&T[wid >> 1][row][col] = res;
        }
    }
    __syncthreads();                      // tile w written by waves 2w,2w+1

    // ---- fused MFMA epilogue: wave pair (2w,2w+1) -> tile w, 2 col-blocks
    // each (wave 2w: c=0,1; wave 2w+1: c=2,3) ----
    const int tw = wid >> 1;
    const int cc0 = (wid & 1) * 2;
    const int mlane = lane & 15;
    const int koff = (lane >> 4) * 8;
    const int vtile = vbase + tw * 16;
    if (vtile < N) {
        int va = vtile + mlane; if (va >= N) va = N - 1;
        f16x8 af[6];
        af[0] = *(const f16x8*)(Y + ((size_t)va << 6) + koff);
        af[1] = *(const f16x8*)(Y + ((size_t)va << 6) + 32 + koff);
        #pragma unroll
        for (int s = 2; s < 6; s++)
            af[s] = *(const f16x8*)&T[tw][mlane][(s - 2) * 32 + koff];

        f32x4 accs[2];
        #pragma unroll
        for (int ci = 0; ci < 2; ci++) {
            int c = cc0 + ci;
            f32x4 acc = {0.f, 0.f, 0.f, 0.f};
            #pragma unroll
            for (int s = 0; s < 6; s++) {
                int k = s * 32 + koff;
                const f16* bp = Wf + (k >> 6) * 4096 + (c * 16 + mlane) * 64 + (k & 63);
                f16x8 bf = *(const f16x8*)bp;
                acc = __builtin_amdgcn_mfma_f32_16x16x32_f16(af[s], bf, acc, 0, 0, 0);
            }
            accs[ci] = acc;
        }

        // C/D layout: col = lane&15, row = (lane>>4)*4 + reg
        const int mrow0 = (lane >> 4) * 4;
        #pragma unroll
        for (int reg = 0; reg < 4; reg++) {
            int vl = tw * 16 + mrow0 + reg;
            int vv = vbase + vl;
            if (vv >= N) continue;
            int lk = 4 * (vl >> 1) + 2 * (vl & 1);
            float cO = (float)cnt[lk], cI = (float)cnt[lk + 1];
            #pragma unroll
            for (int ci = 0; ci < 2; ci++) {
                int j = (cc0 + ci) * 16 + mlane;
                out[(size_t)vv * DF + j] = accs[ci][reg] + b_S[j] + cO * b_O[j] + cI * b_I[j];
            }
        }
    }
}

extern "C" void kernel_launch(void* const* d_in, const int* in_sizes, int n_in,
                              void* d_out, int out_size, void* d_ws, size_t ws_size,
                              hipStream_t stream) {
    const float* x   = (const float*)d_in[0];
    const float* r   = (const float*)d_in[1];
    const int*   src = (const int*)d_in[2];
    const int*   dst = (const int*)d_in[3];
    const float* W_O = (const float*)d_in[4];
    const float* b_O = (const float*)d_in[5];
    const float* W_I = (const float*)d_in[6];
    const float* b_I = (const float*)d_in[7];
    const float* W_S = (const float*)d_in[8];
    const float* b_S = (const float*)d_in[9];
    const float* W_R = (const float*)d_in[10];
    const float* b_R = (const float*)d_in[11];
    float* out = (float*)d_out;

    const int N = in_sizes[0] / DF;
    const int E = in_sizes[2];
    const int half = E / 2;
    const int M = 2 * N;                 // keys: (dst<<1)|isI
    const int NB = (M + 255) >> 8;       // 256 keys per bucket (NB <= NBMAX)

    // ws: Wf[3*4096] f16 | ytab[N*64] f16 | cur[NB*CPAD] | pairBuf[NB*BCAP]
    f16* Wf = (f16*)d_ws;
    f16* ytab = Wf + 3 * 4096;
    int* cur = (int*)(ytab + (size_t)N * 64);
    unsigned int* pairBuf = (unsigned int*)(cur + (size_t)NB * CPAD);

    hipMemsetAsync(cur, 0, (size_t)NB * CPAD * sizeof(int), stream);

    const int SB = (E + SCHUNK - 1) / SCHUNK;          // scatter blocks
    const int PB = (N * 32 + 511) / 512;               // prep blocks
    scatter_prep<<<SB + PB, 512, 0, stream>>>(src, dst, cur, pairBuf,
                                              E, half, NB, SB, PB,
                                              x, r, ytab,
                                              W_S, W_O, W_I, Wf,
                                              W_R, b_R, out, N);

    sort_gather_gemv<<<NB, 1024, 0, stream>>>(pairBuf, cur, ytab, Wf,
                                              b_O, b_I, b_S, out, N, M);
}

// Round 5
// 167.282 us; speedup vs baseline: 1.1146x; 1.1132x over previous
//
#include <hip/hip_runtime.h>

// CompGraphConv round 14: Wf -> LDS in the fused kernel's epilogue.
//
// Round 13 (186 us, flat): occupancy 36->58% but BW pinned at 1.33 TB/s.
// Round-11 comparison isolates the cost: same sort+gather at same traffic
// ran 42.8 us; the MFMA epilogue adds +27 us occupancy-INdependent. The
// epilogue re-reads Wf from global per tile (~3K L1 line-requests/block),
// doubling the per-CU VMEM request load that the random ytab gathers
// already saturate. Fix: stage Wf (24 KB) into LDS once per block with an
// XOR-swizzled 16B-slot layout; B-frags now come from the DS pipe, off the
// VMEM path. Also: ent[ne++] scratch (rule #20) -> named regs; out stores
// nontemporal (write-once, keep L2 for ytab).

#define DF 64
#define BCAP 2560           // entries per bucket: mean 1534, +26 sigma
#define CPAD 16             // ints per cursor (one 64B line each)
#define NBMAX 1024          // max coarse buckets (NB = ceil(2N/256) = 782)
#define SCHUNK 4096         // edges per scatter block
typedef _Float16 f16;
typedef f16 f16x8 __attribute__((ext_vector_type(8)));
typedef f16 f16x4 __attribute__((ext_vector_type(4)));
typedef f16 f16x2 __attribute__((ext_vector_type(2)));
typedef float f32x4 __attribute__((ext_vector_type(4)));

// K1: blocks [0,SB) = block-local LDS edge binning; blocks [SB,SB+PB) =
// y = x - r into compact ytab + W -> f16 Wf; last block also r_transform.
__global__ __launch_bounds__(512) void scatter_prep(
    const int* __restrict__ src, const int* __restrict__ dst,
    int* __restrict__ cur, unsigned int* __restrict__ pairBuf,
    int E, int half, int NB, int SB, int PB,
    const float* __restrict__ x, const float* __restrict__ r,
    f16* __restrict__ ytab,
    const float* __restrict__ W_S, const float* __restrict__ W_O,
    const float* __restrict__ W_I, f16* __restrict__ Wf,
    const float* __restrict__ W_R, const float* __restrict__ b_R,
    float* __restrict__ out, int N) {
    int t = threadIdx.x;
    if ((int)blockIdx.x < SB) {
        __shared__ int cnt[NBMAX];        // histogram, then reused as cursor
        int e0 = blockIdx.x * SCHUNK;
        int n = E - e0; if (n > SCHUNK) n = SCHUNK;
        for (int k = t; k < NBMAX; k += 512) cnt[k] = 0;
        __syncthreads();

        unsigned int ent[SCHUNK / 512];
        int bk[SCHUNK / 512];
        #pragma unroll
        for (int i = 0; i < SCHUNK / 512; i++) {
            int idx = t + i * 512;
            bk[i] = -1;
            if (idx < n) {
                int e = e0 + idx;
                int s = __builtin_nontemporal_load(src + e);
                int d = __builtin_nontemporal_load(dst + e);
                int key = (d << 1) | (e >= half ? 1 : 0);
                int b = key >> 8;         // b < NB <= NBMAX
                ent[i] = (unsigned int)s | ((unsigned int)(key & 255) << 24);
                bk[i] = b;
                atomicAdd(&cnt[b], 1);
            }
        }
        __syncthreads();
        // reserve per-bucket runs: ONE global atomic per (block,bucket)
        for (int k = t; k < NB; k += 512) {
            int c = cnt[k];
            cnt[k] = (c > 0) ? atomicAdd(&cur[k * CPAD], c) : 0;
        }
        __syncthreads();
        #pragma unroll
        for (int i = 0; i < SCHUNK / 512; i++) {
            if (bk[i] >= 0) {
                int pos = atomicAdd(&cnt[bk[i]], 1);
                if (pos < BCAP)
                    pairBuf[(size_t)bk[i] * BCAP + pos] = ent[i];
            }
        }
    } else {
        int tt = ((int)blockIdx.x - SB) * 512 + t;
        int ny = N * 32;                  // f16x2 pairs of y
        if (tt < ny) {
            int v = tt >> 5, k = (tt & 31) * 2;
            float y0 = x[(size_t)v * DF + k]     - r[k];
            float y1 = x[(size_t)v * DF + k + 1] - r[k + 1];
            f16x2 p = {(f16)y0, (f16)y1};
            *(f16x2*)(ytab + (size_t)v * 64 + k) = p;
        }
        if (tt < 6144) {                  // 3*4096 weight elems as pairs
            int w = tt / 2048;
            int i = (tt % 2048) * 2;
            const float* W = (w == 0) ? W_S : (w == 1) ? W_O : W_I;
            f16x2 p = {(f16)W[i], (f16)W[i + 1]};
            *(f16x2*)(Wf + w * 4096 + i) = p;
        }
        if ((int)blockIdx.x == SB + PB - 1 && t < 64) {
            float s = b_R[t];
            #pragma unroll 16
            for (int k = 0; k < 64; k++) s += r[k] * W_R[t * 64 + k];
            out[(size_t)N * DF + t] = s;
        }
    }
}

// K2: per-bucket counting sort (sorted list in LDS) + gather + fused MFMA
// epilogue. 1024 thr = 16 waves x 4 pairs; wave pair (2w,2w+1) produces
// tile w in T[w][16][136]; barrier; wave 2w computes col-blocks 0,1 and
// wave 2w+1 col-blocks 2,3 via mfma_f32_16x16x32_f16. B-frags come from
// WfL (LDS copy of Wf, XOR-swizzled 16B slots: slot = c16 ^ (row&7)) so
// the epilogue issues NO global loads except the 2 coalesced ytab rows.
__global__ __launch_bounds__(1024) void sort_gather_gemv(
    unsigned int* __restrict__ pairBuf, const int* __restrict__ cur,
    const f16* __restrict__ Y, const f16* __restrict__ Wf,
    const float* __restrict__ b_O, const float* __restrict__ b_I,
    const float* __restrict__ b_S, float* __restrict__ out,
    int N, int M) {
    __shared__ unsigned int S[2048 + 8];  // sorted src, +8 zero pad for tail
    __shared__ int cnt[256];
    __shared__ int pos[256];
    __shared__ f16 T[8][16][136];         // per-tile window staging
    __shared__ f16 WfL[3 * 4096];         // swizzled LDS copy of Wf (24 KB)
    int b = blockIdx.x, t = threadIdx.x;

    // stage Wf -> LDS (1536 16B chunks; swizzle slot index with row&7)
    for (int c = t; c < 1536; c += 1024) {
        f16x8 w = *(const f16x8*)(Wf + (c << 3));
        int sub = c >> 9;                 // weight matrix 0..2
        int rr = (c >> 3) & 63;           // output row within matrix
        int c16 = c & 7;                  // 16B slot within row
        *(f16x8*)((char*)WfL + sub * 8192 + rr * 128 +
                  (((c16 ^ rr) & 7) << 4)) = w;
    }
    if (t < 256) cnt[t] = 0;
    __syncthreads();
    int n = cur[b * CPAD];
    if (n > 2048) n = 2048;               // +13 sigma cap, statistically never
    const unsigned int* seg = pairBuf + (size_t)b * BCAP;
    bool h0 = (t < n), h1 = (t + 1024 < n);   // named regs, no scratch array
    unsigned int p0 = 0, p1 = 0;
    if (h0) p0 = seg[t];
    if (h1) p1 = seg[t + 1024];
    if (h0) atomicAdd(&cnt[p0 >> 24], 1);
    if (h1) atomicAdd(&cnt[p1 >> 24], 1);
    __syncthreads();
    int v = 0, incl = 0;
    if (t < 256) { v = cnt[t]; pos[t] = v; }
    __syncthreads();
    #pragma unroll
    for (int s = 1; s < 256; s <<= 1) {
        int u = 0;
        if (t < 256 && t >= s) u = pos[t - s];
        __syncthreads();
        if (t < 256) pos[t] += u;
        __syncthreads();
    }
    if (t < 256) incl = pos[t];
    __syncthreads();
    if (t < 256) pos[t] = incl - v;       // exclusive cursor for the scatter
    __syncthreads();
    if (h0) { int loc = atomicAdd(&pos[p0 >> 24], 1); S[loc] = p0 & 0xFFFFFFu; }
    if (h1) { int loc = atomicAdd(&pos[p1 >> 24], 1); S[loc] = p1 & 0xFFFFFFu; }
    __syncthreads();
    if (t < 8) S[n + t] = 0;              // zero tail pad (n+7 < 2056)
    __syncthreads();
    // post-scatter: pos[l] == inclusive end of run l; cnt[l] == its length

    const int wid = t >> 6, lane = t & 63;
    const int g = lane >> 4, q = lane & 15;
    const int vbase = b * 128;
    const f16x2 zz = {(f16)0.f, (f16)0.f};

    for (int i = 0; i < 4; i++) {
        int pp = wid * 4 + i;             // pair index within bucket
        int v0 = vbase + 2 * pp, v1 = v0 + 1;
        if (v0 >= N) break;
        bool hasV1 = (v1 < N);
        int l0 = 4 * pp;
        int dO0 = cnt[l0], dI0 = cnt[l0 + 1];
        int dO1 = hasV1 ? cnt[l0 + 2] : 0;
        int dI1 = hasV1 ? cnt[l0 + 3] : 0;
        int s0 = pos[l0] - dO0;           // base of run l0 (runs contiguous)
        int t1 = s0 + dO0, t2 = t1 + dI0, t3 = t2 + dO1;
        int end = t3 + dI1;

        f16x2 aA0 = zz, aA1 = zz, a10 = zz, a11 = zz,
              a20 = zz, a21 = zz, a30 = zz, a31 = zz;

        int e = s0;
        for (; e + 8 <= end; e += 8) {
            int eA = e + g, eB = e + g + 4;
            int iA = (int)S[eA];
            int iB = (int)S[eB];
            const f16x2* pa = (const f16x2*)(Y + ((size_t)iA << 6) + 4 * q);
            const f16x2* pb = (const f16x2*)(Y + ((size_t)iB << 6) + 4 * q);
            f16x2 va0 = pa[0], va1 = pa[1];
            f16x2 vb0 = pb[0], vb1 = pb[1];
            aA0 += va0; aA1 += va1;
            a10 += (eA >= t1) ? va0 : zz;  a11 += (eA >= t1) ? va1 : zz;
            a20 += (eA >= t2) ? va0 : zz;  a21 += (eA >= t2) ? va1 : zz;
            a30 += (eA >= t3) ? va0 : zz;  a31 += (eA >= t3) ? va1 : zz;
            aA0 += vb0; aA1 += vb1;
            a10 += (eB >= t1) ? vb0 : zz;  a11 += (eB >= t1) ? vb1 : zz;
            a20 += (eB >= t2) ? vb0 : zz;  a21 += (eB >= t2) ? vb1 : zz;
            a30 += (eB >= t3) ? vb0 : zz;  a31 += (eB >= t3) ? vb1 : zz;
        }
        if (e < end) {                    // masked tail (wave-uniform branch)
            int eA = e + g, eB = e + g + 4;
            bool inA = (eA < end), inB = (eB < end);
            // OOB lanes read the zero pad (eB <= end+6 <= n+6 < 2056)
            int iA = (int)S[eA];
            int iB = (int)S[eB];
            const f16x2* pa = (const f16x2*)(Y + ((size_t)iA << 6) + 4 * q);
            const f16x2* pb = (const f16x2*)(Y + ((size_t)iB << 6) + 4 * q);
            f16x2 va0 = pa[0], va1 = pa[1];
            f16x2 vb0 = pb[0], vb1 = pb[1];
            aA0 += inA ? va0 : zz; aA1 += inA ? va1 : zz;
            a10 += (inA && eA >= t1) ? va0 : zz;  a11 += (inA && eA >= t1) ? va1 : zz;
            a20 += (inA && eA >= t2) ? va0 : zz;  a21 += (inA && eA >= t2) ? va1 : zz;
            a30 += (inA && eA >= t3) ? va0 : zz;  a31 += (inA && eA >= t3) ? va1 : zz;
            aA0 += inB ? vb0 : zz; aA1 += inB ? vb1 : zz;
            a10 += (inB && eB >= t1) ? vb0 : zz;  a11 += (inB && eB >= t1) ? vb1 : zz;
            a20 += (inB && eB >= t2) ? vb0 : zz;  a21 += (inB && eB >= t2) ? vb1 : zz;
            a30 += (inB && eB >= t3) ? vb0 : zz;  a31 += (inB && eB >= t3) ? vb1 : zz;
        }

        // butterfly over the 4 groups, on packed dwords (bit-exact shuffles)
        f16x2 acc[8] = {aA0, aA1, a10, a11, a20, a21, a30, a31};
        #pragma unroll
        for (int k = 0; k < 8; k++) {
            int w = __builtin_bit_cast(int, acc[k]);
            f16x2 u16 = __builtin_bit_cast(f16x2, __shfl_xor(w, 16, 64));
            acc[k] += u16;
            w = __builtin_bit_cast(int, acc[k]);
            f16x2 u32 = __builtin_bit_cast(f16x2, __shfl_xor(w, 32, 64));
            acc[k] += u32;
        }
        // window sums (packed): d0=All-G1, d1=G1-G2, d2=G2-G3, d3=G3
        f16x2 d0l = acc[0] - acc[2], d0h = acc[1] - acc[3];
        f16x2 d1l = acc[2] - acc[4], d1h = acc[3] - acc[5];
        f16x2 d2l = acc[4] - acc[6], d2h = acc[5] - acc[7];
        f16x2 d3l = acc[6],          d3h = acc[7];
        f16x2 wl01 = (g == 0) ? d0l : d1l, wh01 = (g == 0) ? d0h : d1h;
        f16x2 wl23 = (g == 2) ? d2l : d3l, wh23 = (g == 2) ? d2h : d3h;
        f16x2 wl = (g < 2) ? wl01 : wl23,  wh = (g < 2) ? wh01 : wh23;

        int vtgt = (g < 2) ? v0 : v1;
        float d01 = (g == 0) ? (float)dO0 : (float)dI0;
        float d23 = (g == 2) ? (float)dO1 : (float)dI1;
        float dd = (g < 2) ? d01 : d23;
        if (vtgt < N) {
            const f16x2* yp = (const f16x2*)(Y + ((size_t)vtgt << 6) + 4 * q);
            f16x2 y0 = yp[0], y1 = yp[1];
            f16x4 res;
            res[0] = (f16)((float)wl[0] - dd * (float)y0[0]);
            res[1] = (f16)((float)wl[1] - dd * (float)y0[1]);
            res[2] = (f16)((float)wh[0] - dd * (float)y1[0]);
            res[3] = (f16)((float)wh[1] - dd * (float)y1[1]);
            int row = (wid & 1) * 8 + 2 * i + (g >> 1);
            int col = (g & 1) * 64 + 4 * q;
            *(f16x4*)&T[wid >> 1][row][col] = res;
        }
    }
    __syncthreads();                      // tile w written by waves 2w,2w+1

    // ---- fused MFMA epilogue: wave pair (2w,2w+1) -> tile w, 2 col-blocks
    // each (wave 2w: c=0,1; wave 2w+1: c=2,3). B-frags from swizzled WfL ----
    const int tw = wid >> 1;
    const int cc0 = (wid & 1) * 2;
    const int mlane = lane & 15;
    const int koff = (lane >> 4) * 8;
    const int vtile = vbase + tw * 16;
    if (vtile < N) {
        int va = vtile + mlane; if (va >= N) va = N - 1;
        f16x8 af[6];
        af[0] = *(const f16x8*)(Y + ((size_t)va << 6) + koff);
        af[1] = *(const f16x8*)(Y + ((size_t)va << 6) + 32 + koff);
        #pragma unroll
        for (int s = 2; s < 6; s++)
            af[s] = *(const f16x8*)&T[tw][mlane][(s - 2) * 32 + koff];

        f32x4 accs[2];
        #pragma unroll
        for (int ci = 0; ci < 2; ci++) {
            int c = cc0 + ci;
            f32x4 acc = {0.f, 0.f, 0.f, 0.f};
            #pragma unroll
            for (int s = 0; s < 6; s++) {
                int k = s * 32 + koff;
                int rj = c * 16 + mlane;          // output column j
                int sub = k >> 6;
                int c16 = (k & 63) >> 3;
                f16x8 bf = *(const f16x8*)((const char*)WfL + sub * 8192 +
                                           rj * 128 + (((c16 ^ rj) & 7) << 4));
                acc = __builtin_amdgcn_mfma_f32_16x16x32_f16(af[s], bf, acc, 0, 0, 0);
            }
            accs[ci] = acc;
        }

        // C/D layout: col = lane&15, row = (lane>>4)*4 + reg
        const int mrow0 = (lane >> 4) * 4;
        #pragma unroll
        for (int reg = 0; reg < 4; reg++) {
            int vl = tw * 16 + mrow0 + reg;
            int vv = vbase + vl;
            if (vv >= N) continue;
            int lk = 4 * (vl >> 1) + 2 * (vl & 1);
            float cO = (float)cnt[lk], cI = (float)cnt[lk + 1];
            #pragma unroll
            for (int ci = 0; ci < 2; ci++) {
                int j = (cc0 + ci) * 16 + mlane;
                __builtin_nontemporal_store(
                    accs[ci][reg] + b_S[j] + cO * b_O[j] + cI * b_I[j],
                    &out[(size_t)vv * DF + j]);
            }
        }
    }
}

extern "C" void kernel_launch(void* const* d_in, const int* in_sizes, int n_in,
                              void* d_out, int out_size, void* d_ws, size_t ws_size,
                              hipStream_t stream) {
    const float* x   = (const float*)d_in[0];
    const float* r   = (const float*)d_in[1];
    const int*   src = (const int*)d_in[2];
    const int*   dst = (const int*)d_in[3];
    const float* W_O = (const float*)d_in[4];
    const float* b_O = (const float*)d_in[5];
    const float* W_I = (const float*)d_in[6];
    const float* b_I = (const float*)d_in[7];
    const float* W_S = (const float*)d_in[8];
    const float* b_S = (const float*)d_in[9];
    const float* W_R = (const float*)d_in[10];
    const float* b_R = (const float*)d_in[11];
    float* out = (float*)d_out;

    const int N = in_sizes[0] / DF;
    const int E = in_sizes[2];
    const int half = E / 2;
    const int M = 2 * N;                 // keys: (dst<<1)|isI
    const int NB = (M + 255) >> 8;       // 256 keys per bucket (NB <= NBMAX)

    // ws: Wf[3*4096] f16 | ytab[N*64] f16 | cur[NB*CPAD] | pairBuf[NB*BCAP]
    f16* Wf = (f16*)d_ws;
    f16* ytab = Wf + 3 * 4096;
    int* cur = (int*)(ytab + (size_t)N * 64);
    unsigned int* pairBuf = (unsigned int*)(cur + (size_t)NB * CPAD);

    hipMemsetAsync(cur, 0, (size_t)NB * CPAD * sizeof(int), stream);

    const int SB = (E + SCHUNK - 1) / SCHUNK;          // scatter blocks
    const int PB = (N * 32 + 511) / 512;               // prep blocks
    scatter_prep<<<SB + PB, 512, 0, stream>>>(src, dst, cur, pairBuf,
                                              E, half, NB, SB, PB,
                                              x, r, ytab,
                                              W_S, W_O, W_I, Wf,
                                              W_R, b_R, out, N);

    sort_gather_gemv<<<NB, 1024, 0, stream>>>(pairBuf, cur, ytab, Wf,
                                              b_O, b_I, b_S, out, N, M);
}

// Round 8
// 160.457 us; speedup vs baseline: 1.1620x; 1.0425x over previous
//
#include <hip/hip_runtime.h>

// CompGraphConv round 17: consolidation after bisection.
//
// Rounds 15 & 16 failed with BITWISE-IDENTICAL absmax 77.125; round 16 had
// reverted scatter/prep to round-14 verbatim, so the 16-stride/f16x4
// gather rewrite is isolated as the poison (mechanism not identified by
// inspection; lever parked). This round: sort_gather_gemv = round-14
// VERBATIM (last passing, 50.2 us). Banked instead: the re-audited
// round-15 scatter_prep -- SCHUNK 8192 @ 1024 thr (reserve atomics
// 230K -> 115K, mean run 5.2 -> 10.5 entries) and f16x8-vectorized prep
// (4x fewer threads, aligned 16B stores).

#define DF 64
#define BCAP 2560           // entries per bucket: mean 1534, +26 sigma
#define CPAD 16             // ints per cursor (one 64B line each)
#define NBMAX 1024          // max coarse buckets (NB = ceil(2N/256) = 782)
#define SCHUNK 8192         // edges per scatter block
typedef _Float16 f16;
typedef f16 f16x8 __attribute__((ext_vector_type(8)));
typedef f16 f16x4 __attribute__((ext_vector_type(4)));
typedef f16 f16x2 __attribute__((ext_vector_type(2)));
typedef float f32x4 __attribute__((ext_vector_type(4)));

// K1: blocks [0,SB) = block-local LDS edge binning; blocks [SB,SB+PB) =
// y = x - r into compact ytab + W -> f16 Wf; last block also r_transform.
__global__ __launch_bounds__(1024) void scatter_prep(
    const int* __restrict__ src, const int* __restrict__ dst,
    int* __restrict__ cur, unsigned int* __restrict__ pairBuf,
    int E, int half, int NB, int SB, int PB,
    const float* __restrict__ x, const float* __restrict__ r,
    f16* __restrict__ ytab,
    const float* __restrict__ W_S, const float* __restrict__ W_O,
    const float* __restrict__ W_I, f16* __restrict__ Wf,
    const float* __restrict__ W_R, const float* __restrict__ b_R,
    float* __restrict__ out, int N) {
    int t = threadIdx.x;
    if ((int)blockIdx.x < SB) {
        __shared__ int cnt[NBMAX];        // histogram, then reused as cursor
        int e0 = blockIdx.x * SCHUNK;
        int n = E - e0; if (n > SCHUNK) n = SCHUNK;
        for (int k = t; k < NBMAX; k += 1024) cnt[k] = 0;
        __syncthreads();

        unsigned int ent[SCHUNK / 1024];
        int bk[SCHUNK / 1024];
        #pragma unroll
        for (int i = 0; i < SCHUNK / 1024; i++) {
            int idx = t + i * 1024;
            bk[i] = -1;
            if (idx < n) {
                int e = e0 + idx;
                int s = __builtin_nontemporal_load(src + e);
                int d = __builtin_nontemporal_load(dst + e);
                int key = (d << 1) | (e >= half ? 1 : 0);
                int b = key >> 8;         // b < NB <= NBMAX
                ent[i] = (unsigned int)s | ((unsigned int)(key & 255) << 24);
                bk[i] = b;
                atomicAdd(&cnt[b], 1);
            }
        }
        __syncthreads();
        // reserve per-bucket runs: ONE global atomic per (block,bucket)
        for (int k = t; k < NB; k += 1024) {
            int c = cnt[k];
            cnt[k] = (c > 0) ? atomicAdd(&cur[k * CPAD], c) : 0;
        }
        __syncthreads();
        #pragma unroll
        for (int i = 0; i < SCHUNK / 1024; i++) {
            if (bk[i] >= 0) {
                int pos = atomicAdd(&cnt[bk[i]], 1);
                if (pos < BCAP)
                    pairBuf[(size_t)bk[i] * BCAP + pos] = ent[i];
            }
        }
    } else {
        int blk = (int)blockIdx.x - SB;
        int tt = blk * 1024 + t;
        int ny8 = N * 8;                  // f16x8 chunks of y
        if (tt < ny8) {
            int v = tt >> 3, k = (tt & 7) * 8;
            const float* xr = x + (size_t)v * DF + k;
            f32x4 xa = *(const f32x4*)xr;
            f32x4 xb = *(const f32x4*)(xr + 4);
            f16x8 o;
            #pragma unroll
            for (int j = 0; j < 4; j++) {
                o[j]     = (f16)(xa[j] - r[k + j]);
                o[j + 4] = (f16)(xb[j] - r[k + 4 + j]);
            }
            *(f16x8*)(ytab + (size_t)v * 64 + k) = o;
        }
        if (tt < 1536) {                  // 3*4096 weight elems as f16x8
            int w = tt >> 9;
            int i = (tt & 511) * 8;
            const float* W = (w == 0) ? W_S : (w == 1) ? W_O : W_I;
            f32x4 wa = *(const f32x4*)(W + i);
            f32x4 wb = *(const f32x4*)(W + i + 4);
            f16x8 o;
            #pragma unroll
            for (int j = 0; j < 4; j++) {
                o[j] = (f16)wa[j];
                o[j + 4] = (f16)wb[j];
            }
            *(f16x8*)(Wf + w * 4096 + i) = o;
        }
        if (blk == PB - 1 && t < 64) {
            float s = b_R[t];
            #pragma unroll 16
            for (int k = 0; k < 64; k++) s += r[k] * W_R[t * 64 + k];
            out[(size_t)N * DF + t] = s;
        }
    }
}

// K2: per-bucket counting sort (sorted list in LDS) + gather + fused MFMA
// epilogue. ROUND-14 VERBATIM (last passing version). 1024 thr = 16 waves
// x 4 pairs; wave pair (2w,2w+1) produces tile w in T[w][16][136];
// barrier; wave 2w computes col-blocks 0,1 and wave 2w+1 col-blocks 2,3
// via mfma_f32_16x16x32_f16. B-frags from WfL (LDS copy, XOR-swizzled).
__global__ __launch_bounds__(1024) void sort_gather_gemv(
    unsigned int* __restrict__ pairBuf, const int* __restrict__ cur,
    const f16* __restrict__ Y, const f16* __restrict__ Wf,
    const float* __restrict__ b_O, const float* __restrict__ b_I,
    const float* __restrict__ b_S, float* __restrict__ out,
    int N, int M) {
    __shared__ unsigned int S[2048 + 8];  // sorted src, +8 zero pad for tail
    __shared__ int cnt[256];
    __shared__ int pos[256];
    __shared__ f16 T[8][16][136];         // per-tile window staging
    __shared__ f16 WfL[3 * 4096];         // swizzled LDS copy of Wf (24 KB)
    int b = blockIdx.x, t = threadIdx.x;

    // stage Wf -> LDS (1536 16B chunks; swizzle slot index with row&7)
    for (int c = t; c < 1536; c += 1024) {
        f16x8 w = *(const f16x8*)(Wf + (c << 3));
        int sub = c >> 9;                 // weight matrix 0..2
        int rr = (c >> 3) & 63;           // output row within matrix
        int c16 = c & 7;                  // 16B slot within row
        *(f16x8*)((char*)WfL + sub * 8192 + rr * 128 +
                  (((c16 ^ rr) & 7) << 4)) = w;
    }
    if (t < 256) cnt[t] = 0;
    __syncthreads();
    int n = cur[b * CPAD];
    if (n > 2048) n = 2048;               // +13 sigma cap, statistically never
    const unsigned int* seg = pairBuf + (size_t)b * BCAP;
    bool h0 = (t < n), h1 = (t + 1024 < n);   // named regs, no scratch array
    unsigned int p0 = 0, p1 = 0;
    if (h0) p0 = seg[t];
    if (h1) p1 = seg[t + 1024];
    if (h0) atomicAdd(&cnt[p0 >> 24], 1);
    if (h1) atomicAdd(&cnt[p1 >> 24], 1);
    __syncthreads();
    int v = 0, incl = 0;
    if (t < 256) { v = cnt[t]; pos[t] = v; }
    __syncthreads();
    #pragma unroll
    for (int s = 1; s < 256; s <<= 1) {
        int u = 0;
        if (t < 256 && t >= s) u = pos[t - s];
        __syncthreads();
        if (t < 256) pos[t] += u;
        __syncthreads();
    }
    if (t < 256) incl = pos[t];
    __syncthreads();
    if (t < 256) pos[t] = incl - v;       // exclusive cursor for the scatter
    __syncthreads();
    if (h0) { int loc = atomicAdd(&pos[p0 >> 24], 1); S[loc] = p0 & 0xFFFFFFu; }
    if (h1) { int loc = atomicAdd(&pos[p1 >> 24], 1); S[loc] = p1 & 0xFFFFFFu; }
    __syncthreads();
    if (t < 8) S[n + t] = 0;              // zero tail pad (n+7 < 2056)
    __syncthreads();
    // post-scatter: pos[l] == inclusive end of run l; cnt[l] == its length

    const int wid = t >> 6, lane = t & 63;
    const int g = lane >> 4, q = lane & 15;
    const int vbase = b * 128;
    const f16x2 zz = {(f16)0.f, (f16)0.f};

    for (int i = 0; i < 4; i++) {
        int pp = wid * 4 + i;             // pair index within bucket
        int v0 = vbase + 2 * pp, v1 = v0 + 1;
        if (v0 >= N) break;
        bool hasV1 = (v1 < N);
        int l0 = 4 * pp;
        int dO0 = cnt[l0], dI0 = cnt[l0 + 1];
        int dO1 = hasV1 ? cnt[l0 + 2] : 0;
        int dI1 = hasV1 ? cnt[l0 + 3] : 0;
        int s0 = pos[l0] - dO0;           // base of run l0 (runs contiguous)
        int t1 = s0 + dO0, t2 = t1 + dI0, t3 = t2 + dO1;
        int end = t3 + dI1;

        f16x2 aA0 = zz, aA1 = zz, a10 = zz, a11 = zz,
              a20 = zz, a21 = zz, a30 = zz, a31 = zz;

        int e = s0;
        for (; e + 8 <= end; e += 8) {
            int eA = e + g, eB = e + g + 4;
            int iA = (int)S[eA];
            int iB = (int)S[eB];
            const f16x2* pa = (const f16x2*)(Y + ((size_t)iA << 6) + 4 * q);
            const f16x2* pb = (const f16x2*)(Y + ((size_t)iB << 6) + 4 * q);
            f16x2 va0 = pa[0], va1 = pa[1];
            f16x2 vb0 = pb[0], vb1 = pb[1];
            aA0 += va0; aA1 += va1;
            a10 += (eA >= t1) ? va0 : zz;  a11 += (eA >= t1) ? va1 : zz;
            a20 += (eA >= t2) ? va0 : zz;  a21 += (eA >= t2) ? va1 : zz;
            a30 += (eA >= t3) ? va0 : zz;  a31 += (eA >= t3) ? va1 : zz;
            aA0 += vb0; aA1 += vb1;
            a10 += (eB >= t1) ? vb0 : zz;  a11 += (eB >= t1) ? vb1 : zz;
            a20 += (eB >= t2) ? vb0 : zz;  a21 += (eB >= t2) ? vb1 : zz;
            a30 += (eB >= t3) ? vb0 : zz;  a31 += (eB >= t3) ? vb1 : zz;
        }
        if (e < end) {                    // masked tail (wave-uniform branch)
            int eA = e + g, eB = e + g + 4;
            bool inA = (eA < end), inB = (eB < end);
            // OOB lanes read the zero pad (eB <= end+6 <= n+6 < 2056)
            int iA = (int)S[eA];
            int iB = (int)S[eB];
            const f16x2* pa = (const f16x2*)(Y + ((size_t)iA << 6) + 4 * q);
            const f16x2* pb = (const f16x2*)(Y + ((size_t)iB << 6) + 4 * q);
            f16x2 va0 = pa[0], va1 = pa[1];
            f16x2 vb0 = pb[0], vb1 = pb[1];
            aA0 += inA ? va0 : zz; aA1 += inA ? va1 : zz;
            a10 += (inA && eA >= t1) ? va0 : zz;  a11 += (inA && eA >= t1) ? va1 : zz;
            a20 += (inA && eA >= t2) ? va0 : zz;  a21 += (inA && eA >= t2) ? va1 : zz;
            a30 += (inA && eA >= t3) ? va0 : zz;  a31 += (inA && eA >= t3) ? va1 : zz;
            aA0 += inB ? vb0 : zz; aA1 += inB ? vb1 : zz;
            a10 += (inB && eB >= t1) ? vb0 : zz;  a11 += (inB && eB >= t1) ? vb1 : zz;
            a20 += (inB && eB >= t2) ? vb0 : zz;  a21 += (inB && eB >= t2) ? vb1 : zz;
            a30 += (inB && eB >= t3) ? vb0 : zz;  a31 += (inB && eB >= t3) ? vb1 : zz;
        }

        // butterfly over the 4 groups, on packed dwords (bit-exact shuffles)
        f16x2 acc[8] = {aA0, aA1, a10, a11, a20, a21, a30, a31};
        #pragma unroll
        for (int k = 0; k < 8; k++) {
            int w = __builtin_bit_cast(int, acc[k]);
            f16x2 u16 = __builtin_bit_cast(f16x2, __shfl_xor(w, 16, 64));
            acc[k] += u16;
            w = __builtin_bit_cast(int, acc[k]);
            f16x2 u32 = __builtin_bit_cast(f16x2, __shfl_xor(w, 32, 64));
            acc[k] += u32;
        }
        // window sums (packed): d0=All-G1, d1=G1-G2, d2=G2-G3, d3=G3
        f16x2 d0l = acc[0] - acc[2], d0h = acc[1] - acc[3];
        f16x2 d1l = acc[2] - acc[4], d1h = acc[3] - acc[5];
        f16x2 d2l = acc[4] - acc[6], d2h = acc[5] - acc[7];
        f16x2 d3l = acc[6],          d3h = acc[7];
        f16x2 wl01 = (g == 0) ? d0l : d1l, wh01 = (g == 0) ? d0h : d1h;
        f16x2 wl23 = (g == 2) ? d2l : d3l, wh23 = (g == 2) ? d2h : d3h;
        f16x2 wl = (g < 2) ? wl01 : wl23,  wh = (g < 2) ? wh01 : wh23;

        int vtgt = (g < 2) ? v0 : v1;
        float d01 = (g == 0) ? (float)dO0 : (float)dI0;
        float d23 = (g == 2) ? (float)dO1 : (float)dI1;
        float dd = (g < 2) ? d01 : d23;
        if (vtgt < N) {
            const f16x2* yp = (const f16x2*)(Y + ((size_t)vtgt << 6) + 4 * q);
            f16x2 y0 = yp[0], y1 = yp[1];
            f16x4 res;
            res[0] = (f16)((float)wl[0] - dd * (float)y0[0]);
            res[1] = (f16)((float)wl[1] - dd * (float)y0[1]);
            res[2] = (f16)((float)wh[0] - dd * (float)y1[0]);
            res[3] = (f16)((float)wh[1] - dd * (float)y1[1]);
            int row = (wid & 1) * 8 + 2 * i + (g >> 1);
            int col = (g & 1) * 64 + 4 * q;
            *(f16x4*)&T[wid >> 1][row][col] = res;
        }
    }
    __syncthreads();                      // tile w written by waves 2w,2w+1

    // ---- fused MFMA epilogue: wave pair (2w,2w+1) -> tile w, 2 col-blocks
    // each (wave 2w: c=0,1; wave 2w+1: c=2,3). B-frags from swizzled WfL ----
    const int tw = wid >> 1;
    const int cc0 = (wid & 1) * 2;
    const int mlane = lane & 15;
    const int koff = (lane >> 4) * 8;
    const int vtile = vbase + tw * 16;
    if (vtile < N) {
        int va = vtile + mlane; if (va >= N) va = N - 1;
        f16x8 af[6];
        af[0] = *(const f16x8*)(Y + ((size_t)va << 6) + koff);
        af[1] = *(const f16x8*)(Y + ((size_t)va << 6) + 32 + koff);
        #pragma unroll
        for (int s = 2; s < 6; s++)
            af[s] = *(const f16x8*)&T[tw][mlane][(s - 2) * 32 + koff];

        f32x4 accs[2];
        #pragma unroll
        for (int ci = 0; ci < 2; ci++) {
            int c = cc0 + ci;
            f32x4 acc = {0.f, 0.f, 0.f, 0.f};
            #pragma unroll
            for (int s = 0; s < 6; s++) {
                int k = s * 32 + koff;
                int rj = c * 16 + mlane;          // output column j
                int sub = k >> 6;
                int c16 = (k & 63) >> 3;
                f16x8 bf = *(const f16x8*)((const char*)WfL + sub * 8192 +
                                           rj * 128 + (((c16 ^ rj) & 7) << 4));
                acc = __builtin_amdgcn_mfma_f32_16x16x32_f16(af[s], bf, acc, 0, 0, 0);
            }
            accs[ci] = acc;
        }

        // C/D layout: col = lane&15, row = (lane>>4)*4 + reg
        const int mrow0 = (lane >> 4) * 4;
        #pragma unroll
        for (int reg = 0; reg < 4; reg++) {
            int vl = tw * 16 + mrow0 + reg;
            int vv = vbase + vl;
            if (vv >= N) continue;
            int lk = 4 * (vl >> 1) + 2 * (vl & 1);
            float cO = (float)cnt[lk], cI = (float)cnt[lk + 1];
            #pragma unroll
            for (int ci = 0; ci < 2; ci++) {
                int j = (cc0 + ci) * 16 + mlane;
                __builtin_nontemporal_store(
                    accs[ci][reg] + b_S[j] + cO * b_O[j] + cI * b_I[j],
                    &out[(size_t)vv * DF + j]);
            }
        }
    }
}

extern "C" void kernel_launch(void* const* d_in, const int* in_sizes, int n_in,
                              void* d_out, int out_size, void* d_ws, size_t ws_size,
                              hipStream_t stream) {
    const float* x   = (const float*)d_in[0];
    const float* r   = (const float*)d_in[1];
    const int*   src = (const int*)d_in[2];
    const int*   dst = (const int*)d_in[3];
    const float* W_O = (const float*)d_in[4];
    const float* b_O = (const float*)d_in[5];
    const float* W_I = (const float*)d_in[6];
    const float* b_I = (const float*)d_in[7];
    const float* W_S = (const float*)d_in[8];
    const float* b_S = (const float*)d_in[9];
    const float* W_R = (const float*)d_in[10];
    const float* b_R = (const float*)d_in[11];
    float* out = (float*)d_out;

    const int N = in_sizes[0] / DF;
    const int E = in_sizes[2];
    const int half = E / 2;
    const int M = 2 * N;                 // keys: (dst<<1)|isI
    const int NB = (M + 255) >> 8;       // 256 keys per bucket (NB <= NBMAX)

    // ws: Wf[3*4096] f16 | ytab[N*64] f16 | cur[NB*CPAD] | pairBuf[NB*BCAP]
    f16* Wf = (f16*)d_ws;
    f16* ytab = Wf + 3 * 4096;
    int* cur = (int*)(ytab + (size_t)N * 64);
    unsigned int* pairBuf = (unsigned int*)(cur + (size_t)NB * CPAD);

    hipMemsetAsync(cur, 0, (size_t)NB * CPAD * sizeof(int), stream);

    const int SB = (E + SCHUNK - 1) / SCHUNK;          // scatter blocks
    const int PB = (N * 8 + 1023) / 1024;              // prep blocks (f16x8)
    scatter_prep<<<SB + PB, 1024, 0, stream>>>(src, dst, cur, pairBuf,
                                               E, half, NB, SB, PB,
                                               x, r, ytab,
                                               W_S, W_O, W_I, Wf,
                                               W_R, b_R, out, N);

    sort_gather_gemv<<<NB, 1024, 0, stream>>>(pairBuf, cur, ytab, Wf,
                                              b_O, b_I, b_S, out, N, M);
}